// Round 5
// baseline (283.117 us; speedup 1.0000x reference)
//
#include <hip/hip_runtime.h>

typedef short short8 __attribute__((ext_vector_type(8)));
typedef unsigned short us4 __attribute__((ext_vector_type(4)));
typedef float floatx4 __attribute__((ext_vector_type(4)));
typedef unsigned short u16;

#define NN 16384
#define NE 131072
#define NEF_ 128
#define DD 56
#define INV_SQRT3F 0.57735026918962576f
#define PATH_NORMF 0.15811388300841897f

__device__ __forceinline__ float bf2f(u16 u) {
    union { unsigned int i; float f; } v; v.i = ((unsigned int)u) << 16; return v.f;
}
__device__ __forceinline__ u16 f2bf(float f) {
    union { float f; unsigned int i; } v; v.f = f;
    unsigned int r = v.i + 0x7fffu + ((v.i >> 16) & 1u);
    return (u16)(r >> 16);
}

// swizzled sA addressing: 64 rows x 128 u16 (256B rows), XOR bits 3..5 with row&7
// -> GEMM-style column-slice ds_read_b128 spreads across 8 16B slots (2-way = free)
__device__ __forceinline__ int sa_off(int row, int col) {   // returns u16 index
    return (row << 7) + (col ^ ((row & 7) << 3));
}

// ---------------- K0: build FRAG-MAJOR W1f/W2f + edge-src histogram ----------------
__global__ __launch_bounds__(256) void prep(const float* __restrict__ W1,
                                            const float* __restrict__ W2,
                                            u16* __restrict__ W1f,
                                            u16* __restrict__ W2f,
                                            const int* __restrict__ eidx,
                                            int* __restrict__ deg) {
    int b = blockIdx.x;
    if (b < 864) {
        int i = b * 256 + threadIdx.x;   // 221184 = 16384 + 204800
        if (i < 16384) {
            int cc = i >> 13, kk = (i >> 11) & 3, cg = (i >> 9) & 3;
            int lane = (i >> 3) & 63, j = i & 7;
            int q = lane >> 4, m = lane & 15;
            W1f[i] = f2bf(W1[(kk * 32 + q * 8 + j) * 128 + cc * 64 + cg * 16 + m]);
        } else {
            int f = i - 16384;
            int c = f >> 13, kk = (f >> 11) & 3, cg = (f >> 9) & 3;
            int lane = (f >> 3) & 63, j = f & 7;
            int q = lane >> 4, m = lane & 15;
            W2f[f] = f2bf(W2[(kk * 32 + q * 8 + j) * 1600 + c * 64 + cg * 16 + m]);
        }
    } else {
        int e = (b - 864) * 256 + threadIdx.x;
        atomicAdd(&deg[eidx[e]], 1);
    }
}

__global__ __launch_bounds__(1024) void deg_scan(const int* __restrict__ deg,
                                                 int* __restrict__ row_start,
                                                 int* __restrict__ cursor) {
    __shared__ int part[1024];
    const int t = threadIdx.x;
    const int base = t * 16;
    int loc[16];
    int s = 0;
    #pragma unroll
    for (int i = 0; i < 16; i++) { loc[i] = s; s += deg[base + i]; }
    part[t] = s;
    __syncthreads();
    for (int off = 1; off < 1024; off <<= 1) {
        int v = (t >= off) ? part[t - off] : 0;
        __syncthreads();
        part[t] += v;
        __syncthreads();
    }
    int pre = (t == 0) ? 0 : part[t - 1];
    #pragma unroll
    for (int i = 0; i < 16; i++) {
        int v = pre + loc[i];
        row_start[base + i] = v;
        cursor[base + i] = v;
    }
    if (t == 1023) row_start[16384] = pre + s;
}

__global__ __launch_bounds__(256) void edge_scatter(const int* __restrict__ eidx,
                                                    int* __restrict__ cursor,
                                                    int* __restrict__ edge_order) {
    int e = blockIdx.x * 256 + threadIdx.x;
    int p = atomicAdd(&cursor[eidx[e]], 1);
    edge_order[p] = e;
}

// ---------------- K2: fused MLP + tensor product ----------------
// 512 threads = 8 waves: cg = wv&1 (16 w-cols of a 32-col chunk), eh = wv>>1
// (4 edge-tiles of 16).  Per-wave register state is HALF of the round-0 design
// (hc 16, tps+tpv 16, hacc 16), and LDS is 32 KiB (sA swizzled stride-128, no
// b2s, sF 64 rows, 8 KiB W2 chunks) -> target 3 resident blocks/CU (24 waves)
// vs round-0's 2.  W2 chunks are still LDS-broadcast (read once per block),
// 50 chunks double-buffered, one barrier each.
__global__ __launch_bounds__(512, 6) void tpconv(
    const float* __restrict__ node_attr, const float* __restrict__ edge_attr,
    const float* __restrict__ edge_sh, const u16* __restrict__ W1f,
    const float* __restrict__ b1, const u16* __restrict__ W2f,
    const float* __restrict__ b2, const int* __restrict__ eidx,
    const int* __restrict__ edge_order,
    float* __restrict__ tp)
{
    __shared__ __align__(16) char smem[32768];
    u16*   sA  = (u16*)smem;                 // 64x128 u16 swizzled = 16384 (ea, then h; dead after hc)
    u16*   B2a = (u16*)(smem + 16384);       // 8192 B W2 chunk (even parity)
    u16*   B2b = (u16*)smem;                 // 8192 B (odd parity) — overlays sA
    u16*   sF  = (u16*)(smem + 24576);       // 64x64 u16 = 8192 B (xs / dot / xv)
    float* Svec = (float*)smem;              // overlay post-loop: 2*64*25 f32 = 12800 B

    const int t = threadIdx.x;
    const int lane = t & 63;
    const int wv = t >> 6;           // 0..7
    const int m = lane & 15;
    const int q = lane >> 4;
    const int cg = wv & 1;           // TP col-group (16 of 32 chunk cols)
    const int eh = wv >> 1;          // TP edge-tile (16 edges)
    const int p0 = blockIdx.x * 64;  // CSR position base

    const int w2t = (t >> 7) * 2048 + (t & 127) * 8;   // thread offset within a chunk's source

    // early global issues: W2 chunk 0 + W1 fragments (this wave's h col-tile)
    short8 pre = *(const short8*)&W2f[w2t];            // chunk 0: (0>>1)*8192 + (0&1)*1024
    short8 g[4];
    #pragma unroll
    for (int kk = 0; kk < 4; kk++)
        g[kk] = *(const short8*)&W1f[(wv >> 2) * 8192 + (kk * 4 + (wv & 3)) * 512 + lane * 8];

    // stage edge_attr tile (64 gathered rows, fp32 -> bf16, swizzled)
    #pragma unroll
    for (int ii = 0; ii < 4; ii++) {
        int cid = t + 512 * ii;          // 2048 = 64 rows * 32 quads
        int r = cid >> 5, s = cid & 31;
        int e = edge_order[p0 + r];
        const float* src = &edge_attr[(size_t)e * NEF_ + s * 4];
        us4 o;
        o.x = f2bf(src[0]); o.y = f2bf(src[1]); o.z = f2bf(src[2]); o.w = f2bf(src[3]);
        *(us4*)&sA[sa_off(r, s * 4)] = o;
    }
    // per-edge factors: 8 writer-groups per edge (all waves participate)
    {
        int e = t & 63, p = t >> 6;
        int eg = edge_order[p0 + e];
        int nd = eidx[NE + eg];
        const float* na = node_attr + (size_t)nd * DD;
        if (p < 4) {                              // xs rows 0..31
            #pragma unroll
            for (int k = 0; k < 8; k++)
                sF[(p * 8 + k) * 64 + e] = f2bf(na[p * 8 + k]);
        } else if (p == 4) {                      // dot rows 32..39
            const float* sh = edge_sh + (size_t)eg * 4;
            float s0 = sh[1], s1 = sh[2], s2 = sh[3];
            #pragma unroll
            for (int i = 0; i < 8; i++) {
                float d = (na[32 + 3 * i] * s0 + na[33 + 3 * i] * s1 + na[34 + 3 * i] * s2) * INV_SQRT3F;
                sF[(32 + i) * 64 + e] = f2bf(d);
            }
        } else {                                  // xv rows 40..63
            #pragma unroll
            for (int k = 0; k < 8; k++)
                sF[(40 + (p - 5) * 8 + k) * 64 + e] = f2bf(na[32 + (p - 5) * 8 + k]);
        }
    }
    // commit W2 chunk 0 into B2a (region disjoint from sA/sF), prefetch chunk 1
    *(short8*)&B2a[t * 8] = pre;
    pre = *(const short8*)&W2f[1024 + w2t];
    __syncthreads();   // B1: sA(edge_attr) + sF ready

    // ---- h = relu(ea @ W1 + b1): wave wv owns h cols wv*16..wv*16+15 ----
    floatx4 hacc[4];
    {
        float bv = b1[wv * 16 + m];
        #pragma unroll
        for (int rt = 0; rt < 4; rt++) hacc[rt] = (floatx4){bv, bv, bv, bv};
    }
    #pragma unroll
    for (int kk = 0; kk < 4; kk++)
        #pragma unroll
        for (int rt = 0; rt < 4; rt++) {
            short8 a = *(const short8*)&sA[sa_off(rt * 16 + m, kk * 32 + q * 8)];
            hacc[rt] = __builtin_amdgcn_mfma_f32_16x16x32_bf16(a, g[kk], hacc[rt], 0, 0, 0);
        }
    __syncthreads();   // B2: all edge_attr reads drained (h overwrites sA in place)
    #pragma unroll
    for (int rt = 0; rt < 4; rt++)
        #pragma unroll
        for (int r = 0; r < 4; r++) {
            int e = rt * 16 + q * 4 + r;
            float v = hacc[rt][r];
            sA[sa_off(e, wv * 16 + m)] = f2bf(v > 0.f ? v : 0.f);
        }
    __syncthreads();   // B3: h complete

    // h B-fragments for this wave's 16-edge tile (16 VGPR, reused 50x)
    short8 hc[4];
    #pragma unroll
    for (int kk = 0; kk < 4; kk++)
        hc[kk] = *(const short8*)&sA[sa_off(eh * 16 + m, kk * 32 + q * 8)];

    // per-edge sh factors straight from global (L2-resident)
    float ssc, svc0, svc1, svc2;
    {
        int eg = edge_order[p0 + eh * 16 + m];
        const float* sh = edge_sh + (size_t)eg * 4;
        ssc = sh[0]; svc0 = sh[1]; svc1 = sh[2]; svc2 = sh[3];
    }
    floatx4 bias = *(const floatx4*)&b2[cg * 16 + q * 4];   // chunk 0 bias

    __syncthreads();   // B4: hc reads drained -> B2b (sA region) writable

    float tps[4] = {0.f, 0.f, 0.f, 0.f};
    float tpv[4][3];
    #pragma unroll
    for (int r = 0; r < 4; r++) { tpv[r][0] = 0.f; tpv[r][1] = 0.f; tpv[r][2] = 0.f; }

    const int e = eh * 16 + m;

    // ---- 50 chunks (32 w-cols), double-buffered, ONE barrier per chunk ----
    #pragma unroll 2
    for (int c = 0; c < 50; c++) {
        const u16* rb = (c & 1) ? B2b : B2a;
        u16*       wb = (c & 1) ? B2a : B2b;

        floatx4 acc = bias;
        #pragma unroll
        for (int kk = 0; kk < 4; kk++) {
            short8 a = *(const short8*)&rb[kk * 1024 + cg * 512 + lane * 8];
            acc = __builtin_amdgcn_mfma_f32_16x16x32_bf16(a, hc[kk], acc, 0, 0, 0);
        }

        if (c < 49) {
            *(short8*)&wb[t * 8] = pre;                       // commit chunk c+1
            bias = *(const floatx4*)&b2[(c + 1) * 32 + cg * 16 + q * 4];
            if (c < 48)
                pre = *(const short8*)&W2f[(size_t)((c + 2) >> 1) * 8192
                                           + (size_t)(((c + 2) & 1)) * 1024 + w2t];
        }

        // consume (lane holds w[gcol = c*32 + cg*16 + q*4 + r][e])
        if (c < 32) {                       // ss: i = c
            float f = bf2f(sF[c * 64 + e]) * ssc;
            #pragma unroll
            for (int r = 0; r < 4; r++) tps[r] += acc[r] * f;
        } else if (c < 40) {                // vs: i = c-32 -> row c
            float f = bf2f(sF[c * 64 + e]);
            #pragma unroll
            for (int r = 0; r < 4; r++) tps[r] += acc[r] * f;
        } else if (c < 48) {                // sv: i = 4(c-40) + cg*2 + (q>>1), f = xs[i]
            const int i = 4 * (c - 40) + cg * 2 + (q >> 1);
            float f = bf2f(sF[i * 64 + e]);
            #pragma unroll
            for (int r = 0; r < 4; r++) {
                float t0 = acc[r] * f;
                tpv[r][0] += t0 * svc0;
                tpv[r][1] += t0 * svc1;
                tpv[r][2] += t0 * svc2;
            }
        } else {                            // vv: i = 4(c-48) + cg*2 + (q>>1), f = xv[i]*ss
            const int i = 4 * (c - 48) + cg * 2 + (q >> 1);
            float x0 = bf2f(sF[(40 + 3 * i    ) * 64 + e]) * ssc;
            float x1 = bf2f(sF[(40 + 3 * i + 1) * 64 + e]) * ssc;
            float x2 = bf2f(sF[(40 + 3 * i + 2) * 64 + e]) * ssc;
            #pragma unroll
            for (int r = 0; r < 4; r++) {
                tpv[r][0] += acc[r] * x0;
                tpv[r][1] += acc[r] * x1;
                tpv[r][2] += acc[r] * x2;
            }
        }

        __syncthreads();   // chunk c reads + chunk c+1 writes complete
    }

    // ---- out_s fully lane-owned: direct global store (j = cg*16 + q*4 + r) ----
    {
        floatx4 o;
        o.x = tps[0] * PATH_NORMF; o.y = tps[1] * PATH_NORMF;
        o.z = tps[2] * PATH_NORMF; o.w = tps[3] * PATH_NORMF;
        *(floatx4*)&tp[(size_t)(p0 + e) * DD + cg * 16 + q * 4] = o;
    }
    // ---- out_v: fold q-parity in-wave, cross-cg via LDS overlay ----
    #pragma unroll
    for (int r = 0; r < 4; r++)
        #pragma unroll
        for (int mm = 0; mm < 3; mm++) {
            float v = tpv[r][mm];
            v += __shfl_xor(v, 32, 64);
            if (q < 2)
                Svec[cg * 1600 + e * 25 + (q * 4 + r) * 3 + mm] = v;
        }
    __syncthreads();

    {
        int ee = t >> 3, j0 = (t & 7) * 3;
        float* dst = &tp[(size_t)(p0 + ee) * DD + 32 + j0];
        #pragma unroll
        for (int k = 0; k < 3; k++) {
            float v = Svec[ee * 25 + j0 + k] + Svec[1600 + ee * 25 + j0 + k];
            dst[k] = v * PATH_NORMF;
        }
    }
}

// ---------------- K3: contiguous segment-mean + residual + per-block BN partials ----------------
__global__ __launch_bounds__(256) void gather_finalize(
    const float* __restrict__ tp, const int* __restrict__ row_start,
    const float* __restrict__ node_attr,
    float* __restrict__ ybuf, float* __restrict__ partial)
{
    __shared__ float ps[4][72];
    const int wv = threadIdx.x >> 6, lane = threadIdx.x & 63;
    const int n = blockIdx.x * 4 + wv;    // 4096 blocks
    const int beg = row_start[n], end = row_start[n + 1];
    if (lane < 56) {
        float acc = 0.f;
        for (int p = beg; p < end; p++)
            acc += tp[(size_t)p * DD + lane];   // fully coalesced, sequential
        float inv = 1.f / fmaxf((float)(end - beg), 1.f);
        float y = acc * inv + node_attr[(size_t)n * DD + lane];
        ybuf[(size_t)n * DD + lane] = y;
        if (lane < 32) {
            ps[wv][lane] = y;
            ps[wv][32 + lane] = y * y;
        } else {
            float vv = y * y;
            float v1 = __shfl_down(vv, 1, 64);
            float v2 = __shfl_down(vv, 2, 64);
            int l3 = lane - 32;
            if (l3 % 3 == 0) ps[wv][64 + l3 / 3] = vv + v1 + v2;
        }
    }
    __syncthreads();
    const int t = threadIdx.x;
    if (t < 72)
        partial[(size_t)blockIdx.x * 72 + t] = ps[0][t] + ps[1][t] + ps[2][t] + ps[3][t];
}

// ---------------- K4: reduce BN partials (no atomic contention) ----------------
__global__ __launch_bounds__(256) void bn_reduce(const float* __restrict__ partial,
                                                 float* __restrict__ stats)
{
    __shared__ float red[256];
    const int d = blockIdx.x;   // 0..71
    const int t = threadIdx.x;
    float a = 0.f;
    for (int i = t; i < 4096; i += 256) a += partial[(size_t)i * 72 + d];
    red[t] = a;
    __syncthreads();
    for (int off = 128; off > 0; off >>= 1) {
        if (t < off) red[t] += red[t + off];
        __syncthreads();
    }
    if (t == 0) stats[d] = red[0] * (1.f / 16384.f);
}

// ---------------- K5: batch-norm apply + write fp32 output ----------------
__global__ __launch_bounds__(256) void bn_apply(
    const float* __restrict__ ybuf, const float* __restrict__ stats,
    const float* __restrict__ gamma, const float* __restrict__ beta,
    float* __restrict__ out)
{
    const int i = blockIdx.x * 256 + threadIdx.x;   // 3584*256 = 917504
    const int n = i / 56;
    const int d = i - n * 56;
    float y = ybuf[i];
    float o;
    if (d < 32) {
        float mn  = stats[d];
        float var = stats[32 + d] - mn * mn;
        o = (y - mn) * rsqrtf(var + 1e-5f) * gamma[d] + beta[d];
    } else {
        int jv = (d - 32) / 3;
        o = y * rsqrtf(stats[64 + jv] + 1e-5f) * gamma[32 + jv];
    }
    out[i] = o;
}

// ---------------- launch ----------------
extern "C" void kernel_launch(void* const* d_in, const int* in_sizes, int n_in,
                              void* d_out, int out_size, void* d_ws, size_t ws_size,
                              hipStream_t stream)
{
    const float* node_attr = (const float*)d_in[0];
    const float* edge_attr = (const float*)d_in[1];
    const float* edge_sh   = (const float*)d_in[2];
    const float* W1        = (const float*)d_in[3];
    const float* b1        = (const float*)d_in[4];
    const float* W2        = (const float*)d_in[5];
    const float* b2        = (const float*)d_in[6];
    const float* gamma     = (const float*)d_in[7];
    const float* beta      = (const float*)d_in[8];
    const int*   eidx      = (const int*)d_in[9];

    char* ws = (char*)d_ws;
    u16*   W1f        = (u16*)(ws);                  // 32768 B
    u16*   W2f        = (u16*)(ws + 32768);          // 409600   -> 442368
    int*   deg        = (int*)(ws + 442368);         // 65536    -> 507904
    int*   row_start  = (int*)(ws + 507904);         // 65792    -> 573696
    int*   cursor     = (int*)(ws + 573696);         // 65536    -> 639232
    int*   edge_order = (int*)(ws + 639232);         // 524288   -> 1163520
    float* stats      = (float*)(ws + 1163520);      // 512      -> 1164032
    float* partial    = (float*)(ws + 1164032);      // 1179648  -> 2343680
    float* tp         = (float*)(ws + 2343680);      // 29360128 -> 31703808
    float* ybuf       = (float*)(ws + 31703808);     // 3670016  -> 35373824 (~35.4 MB)

    (void)hipMemsetAsync(deg, 0, 65536, stream);
    hipLaunchKernelGGL(prep,            dim3(1376), dim3(256),  0, stream,
                       W1, W2, W1f, W2f, eidx, deg);
    hipLaunchKernelGGL(deg_scan,        dim3(1),    dim3(1024), 0, stream, deg, row_start, cursor);
    hipLaunchKernelGGL(edge_scatter,    dim3(512),  dim3(256),  0, stream, eidx, cursor, edge_order);
    hipLaunchKernelGGL(tpconv,          dim3(2048), dim3(512),  0, stream,
                       node_attr, edge_attr, edge_sh, W1f, b1, W2f, b2, eidx, edge_order, tp);
    hipLaunchKernelGGL(gather_finalize, dim3(4096), dim3(256),  0, stream,
                       tp, row_start, node_attr, ybuf, partial);
    hipLaunchKernelGGL(bn_reduce,       dim3(72),   dim3(256),  0, stream, partial, stats);
    hipLaunchKernelGGL(bn_apply,        dim3(3584), dim3(256),  0, stream,
                       ybuf, stats, gamma, beta, (float*)d_out);
}

// Round 6
// 254.252 us; speedup vs baseline: 1.1135x; 1.1135x over previous
//
#include <hip/hip_runtime.h>

typedef short short8 __attribute__((ext_vector_type(8)));
typedef unsigned short us4 __attribute__((ext_vector_type(4)));
typedef float floatx4 __attribute__((ext_vector_type(4)));
typedef unsigned short u16;

#define NN 16384
#define NE 131072
#define NEF_ 128
#define DD 56
#define INV_SQRT3F 0.57735026918962576f
#define PATH_NORMF 0.15811388300841897f

__device__ __forceinline__ float bf2f(u16 u) {
    union { unsigned int i; float f; } v; v.i = ((unsigned int)u) << 16; return v.f;
}
__device__ __forceinline__ u16 f2bf(float f) {
    union { float f; unsigned int i; } v; v.f = f;
    unsigned int r = v.i + 0x7fffu + ((v.i >> 16) & 1u);
    return (u16)(r >> 16);
}

// swizzled sA addressing: 128 rows x 128 u16 (256B rows), XOR col bits 3..5 with row&7
__device__ __forceinline__ int sa_off(int row, int col) {   // u16 index
    return (row << 7) + (col ^ ((row & 7) << 3));
}

// ---------------- K0: build FRAG-MAJOR W1f/W2f + edge-src histogram ----------------
__global__ __launch_bounds__(256) void prep(const float* __restrict__ W1,
                                            const float* __restrict__ W2,
                                            u16* __restrict__ W1f,
                                            u16* __restrict__ W2f,
                                            const int* __restrict__ eidx,
                                            int* __restrict__ deg) {
    int b = blockIdx.x;
    if (b < 864) {
        int i = b * 256 + threadIdx.x;   // 221184 = 16384 + 204800
        if (i < 16384) {
            int cc = i >> 13, kk = (i >> 11) & 3, cg = (i >> 9) & 3;
            int lane = (i >> 3) & 63, j = i & 7;
            int q = lane >> 4, m = lane & 15;
            W1f[i] = f2bf(W1[(kk * 32 + q * 8 + j) * 128 + cc * 64 + cg * 16 + m]);
        } else {
            int f = i - 16384;
            int c = f >> 13, kk = (f >> 11) & 3, cg = (f >> 9) & 3;
            int lane = (f >> 3) & 63, j = f & 7;
            int q = lane >> 4, m = lane & 15;
            W2f[f] = f2bf(W2[(kk * 32 + q * 8 + j) * 1600 + c * 64 + cg * 16 + m]);
        }
    } else {
        int e = (b - 864) * 256 + threadIdx.x;
        atomicAdd(&deg[eidx[e]], 1);
    }
}

__global__ __launch_bounds__(1024) void deg_scan(const int* __restrict__ deg,
                                                 int* __restrict__ row_start,
                                                 int* __restrict__ cursor) {
    __shared__ int part[1024];
    const int t = threadIdx.x;
    const int base = t * 16;
    int loc[16];
    int s = 0;
    #pragma unroll
    for (int i = 0; i < 16; i++) { loc[i] = s; s += deg[base + i]; }
    part[t] = s;
    __syncthreads();
    for (int off = 1; off < 1024; off <<= 1) {
        int v = (t >= off) ? part[t - off] : 0;
        __syncthreads();
        part[t] += v;
        __syncthreads();
    }
    int pre = (t == 0) ? 0 : part[t - 1];
    #pragma unroll
    for (int i = 0; i < 16; i++) {
        int v = pre + loc[i];
        row_start[base + i] = v;
        cursor[base + i] = v;
    }
    if (t == 1023) row_start[16384] = pre + s;
}

__global__ __launch_bounds__(256) void edge_scatter(const int* __restrict__ eidx,
                                                    int* __restrict__ cursor,
                                                    int* __restrict__ edge_order) {
    int e = blockIdx.x * 256 + threadIdx.x;
    int p = atomicAdd(&cursor[eidx[e]], 1);
    edge_order[p] = e;
}

// ---------------- K2: fused MLP + tensor product, 128 edges/block ----------------
// 512 threads = 8 waves: cg = wv&1 (32 of the chunk's 64 cols), ew = wv>>1
// (32 edges = 2 et-tiles).  vs R0 (64 edges/block): half the blocks -> half the
// W2 L2 re-streaming (410 MB) and half the barrier/drain count per edge; each
// A-fragment ds_read feeds 2 et-MFMAs (16 MFMA per wave per chunk vs 8).
// tp writes go back through padded LDS overlays -> coalesced 56-float rows
// (R5's direct scattered stores caused 2.6x WRITE_SIZE via partial-line RMW).
__global__ __launch_bounds__(512, 4) void tpconv(
    const float* __restrict__ node_attr, const float* __restrict__ edge_attr,
    const float* __restrict__ edge_sh, const u16* __restrict__ W1f,
    const float* __restrict__ b1, const u16* __restrict__ W2f,
    const float* __restrict__ b2, const int* __restrict__ eidx,
    const int* __restrict__ edge_order,
    float* __restrict__ tp)
{
    __shared__ __align__(16) char smem[73728];   // 72 KiB -> 2 blocks/CU
    u16*   sA  = (u16*)smem;                 // [0,32K): 128x128 u16 swizzled (ea, then h)
    u16*   sF  = (u16*)(smem + 32768);       // [32K,48K): 64 rows x 128 edges
    u16*   B2a = (u16*)(smem + 49152);       // [48K,64K): 16 KB W2 chunk (even parity)
    u16*   B2b = (u16*)smem;                 // [0,16K): odd parity (overlays dead sA rows 0..63)
    float* b2s = (float*)(smem + 65536);     // [64K,70.4K): 1600 f32
    float* Ssc  = (float*)smem;              // post-loop: 2*128*33 f32 = 33792 B
    float* Svec = (float*)(smem + 33792);    // post-loop: 2*128*25 f32 = 25600 -> 59392

    const int t = threadIdx.x;
    const int lane = t & 63;
    const int wv = t >> 6;           // 0..7
    const int m = lane & 15;
    const int q = lane >> 4;
    const int cg = wv & 1;           // col half (32 of 64 chunk cols)
    const int ew = wv >> 1;          // edge-group (32 edges)
    const int p0 = blockIdx.x * 128; // CSR position base

    // early prefetch: W2 chunk 0 (2 x 16B per thread, contiguous)
    short8 pre[2];
    #pragma unroll
    for (int ii = 0; ii < 2; ii++)
        pre[ii] = *(const short8*)&W2f[ii * 4096 + t * 8];

    for (int i = t; i < 1600; i += 512) b2s[i] = b2[i];

    // W1 fragments for this wave's h col-tile (direct from L2)
    short8 g[4];
    #pragma unroll
    for (int kk = 0; kk < 4; kk++)
        g[kk] = *(const short8*)&W1f[(wv >> 2) * 8192 + (kk * 4 + (wv & 3)) * 512 + lane * 8];

    // stage edge_attr tile (128 gathered rows, fp32 -> bf16, swizzled)
    #pragma unroll
    for (int ii = 0; ii < 8; ii++) {
        int cid = t + 512 * ii;          // 4096 = 128 rows * 32 quads
        int r = cid >> 5, s = cid & 31;
        int e = edge_order[p0 + r];
        const float* src = &edge_attr[(size_t)e * NEF_ + s * 4];
        us4 o;
        o.x = f2bf(src[0]); o.y = f2bf(src[1]); o.z = f2bf(src[2]); o.w = f2bf(src[3]);
        *(us4*)&sA[sa_off(r, s * 4)] = o;
    }
    // per-edge factors: 4 writer-groups per edge
    {
        int e = t & 127, p = t >> 7;
        int eg = edge_order[p0 + e];
        int nd = eidx[NE + eg];
        const float* na = node_attr + (size_t)nd * DD;
        if (p < 2) {                              // xs rows 0..31
            #pragma unroll
            for (int k = 0; k < 16; k++)
                sF[(p * 16 + k) * 128 + e] = f2bf(na[p * 16 + k]);
        } else if (p == 2) {                      // dot rows 32..39
            const float* sh = edge_sh + (size_t)eg * 4;
            float s0 = sh[1], s1 = sh[2], s2 = sh[3];
            #pragma unroll
            for (int i = 0; i < 8; i++) {
                float d = (na[32 + 3 * i] * s0 + na[33 + 3 * i] * s1 + na[34 + 3 * i] * s2) * INV_SQRT3F;
                sF[(32 + i) * 128 + e] = f2bf(d);
            }
        } else {                                  // xv rows 40..63
            #pragma unroll
            for (int k = 0; k < 24; k++)
                sF[(40 + k) * 128 + e] = f2bf(na[32 + k]);
        }
    }
    // commit W2 chunk 0 -> B2a (disjoint region), prefetch chunk 1
    #pragma unroll
    for (int ii = 0; ii < 2; ii++)
        *(short8*)&B2a[ii * 4096 + t * 8] = pre[ii];
    #pragma unroll
    for (int ii = 0; ii < 2; ii++)
        pre[ii] = *(const short8*)&W2f[8192 + ii * 4096 + t * 8];
    __syncthreads();   // B1: sA (edge_attr) + sF + B2a ready

    // ---- h = relu(ea @ W1 + b1): wave wv owns h cols wv*16..wv*16+15, all 128 edges ----
    floatx4 hacc[8];
    {
        float bv = b1[wv * 16 + m];
        #pragma unroll
        for (int rt = 0; rt < 8; rt++) hacc[rt] = (floatx4){bv, bv, bv, bv};
    }
    #pragma unroll
    for (int kk = 0; kk < 4; kk++)
        #pragma unroll
        for (int rt = 0; rt < 8; rt++) {
            short8 a = *(const short8*)&sA[sa_off(rt * 16 + m, kk * 32 + q * 8)];
            hacc[rt] = __builtin_amdgcn_mfma_f32_16x16x32_bf16(a, g[kk], hacc[rt], 0, 0, 0);
        }
    __syncthreads();   // B2: edge_attr reads drained (h overwrites sA in place)
    #pragma unroll
    for (int rt = 0; rt < 8; rt++)
        #pragma unroll
        for (int r = 0; r < 4; r++) {
            int e = rt * 16 + q * 4 + r;
            float v = hacc[rt][r];
            sA[sa_off(e, wv * 16 + m)] = f2bf(v > 0.f ? v : 0.f);
        }
    __syncthreads();   // B3: h complete

    // h B-fragments for this wave's 2 edge-tiles (32 VGPR, reused 25x)
    const int e0 = ew * 32 + m;
    const int e1 = ew * 32 + 16 + m;
    short8 hc[2][4];
    #pragma unroll
    for (int et = 0; et < 2; et++)
        #pragma unroll
        for (int kk = 0; kk < 4; kk++)
            hc[et][kk] = *(const short8*)&sA[sa_off(ew * 32 + et * 16 + m, kk * 32 + q * 8)];

    // per-edge sh factors (L2-resident)
    float ssc[2], svc[2][3];
    #pragma unroll
    for (int et = 0; et < 2; et++) {
        int eg = edge_order[p0 + ew * 32 + et * 16 + m];
        const float* sh = edge_sh + (size_t)eg * 4;
        ssc[et] = sh[0]; svc[et][0] = sh[1]; svc[et][1] = sh[2]; svc[et][2] = sh[3];
    }
    __syncthreads();   // B4: hc reads drained -> B2b (sA rows 0..63) writable

    float tps[2][2][4];   // [et][ct][r]: out_s[e][j = ct*16+q*4+r], partial over cg
    float tpv[2][4][3];   // [et][r][mm]: out_v[e][jv=(q&1)*4+r][mm], partial over cg/(q>>1)
    #pragma unroll
    for (int et = 0; et < 2; et++)
        #pragma unroll
        for (int r = 0; r < 4; r++) {
            tps[et][0][r] = 0.f; tps[et][1][r] = 0.f;
            tpv[et][r][0] = 0.f; tpv[et][r][1] = 0.f; tpv[et][r][2] = 0.f;
        }

    // ---- 25 chunks (64 w-cols), double-buffered, ONE barrier per chunk ----
    for (int c = 0; c < 25; c++) {
        const u16* rb = (c & 1) ? B2b : B2a;
        u16*       wb = (c & 1) ? B2a : B2b;

        floatx4 acc[2][2];   // [ct][et]
        #pragma unroll
        for (int ct = 0; ct < 2; ct++) {
            floatx4 bias = *(const floatx4*)&b2s[c * 64 + cg * 32 + ct * 16 + q * 4];
            acc[ct][0] = bias; acc[ct][1] = bias;
        }
        #pragma unroll
        for (int kk = 0; kk < 4; kk++)
            #pragma unroll
            for (int ct = 0; ct < 2; ct++) {
                short8 a = *(const short8*)&rb[(kk * 4 + cg * 2 + ct) * 512 + lane * 8];
                acc[ct][0] = __builtin_amdgcn_mfma_f32_16x16x32_bf16(a, hc[0][kk], acc[ct][0], 0, 0, 0);
                acc[ct][1] = __builtin_amdgcn_mfma_f32_16x16x32_bf16(a, hc[1][kk], acc[ct][1], 0, 0, 0);
            }

        if (c < 24) {
            #pragma unroll
            for (int ii = 0; ii < 2; ii++)
                *(short8*)&wb[ii * 4096 + t * 8] = pre[ii];
            if (c < 23) {
                #pragma unroll
                for (int ii = 0; ii < 2; ii++)
                    pre[ii] = *(const short8*)&W2f[(size_t)(c + 2) * 8192 + ii * 4096 + t * 8];
            }
        }

        // consume (lane holds w[gcol = c*64 + cg*32 + ct*16 + q*4 + r][e])
        if (c < 16) {                       // ss: i = 2c + cg, f = xs[i]*ss
            const int i = 2 * c + cg;
            #pragma unroll
            for (int et = 0; et < 2; et++) {
                float f = bf2f(sF[i * 128 + (et ? e1 : e0)]) * ssc[et];
                #pragma unroll
                for (int ct = 0; ct < 2; ct++)
                    #pragma unroll
                    for (int r = 0; r < 4; r++) tps[et][ct][r] += acc[ct][et][r] * f;
            }
        } else if (c < 20) {                // vs: i = 2(c-16) + cg, f = dot[i]
            const int i = 2 * (c - 16) + cg;
            #pragma unroll
            for (int et = 0; et < 2; et++) {
                float f = bf2f(sF[(32 + i) * 128 + (et ? e1 : e0)]);
                #pragma unroll
                for (int ct = 0; ct < 2; ct++)
                    #pragma unroll
                    for (int r = 0; r < 4; r++) tps[et][ct][r] += acc[ct][et][r] * f;
            }
        } else if (c < 24) {                // sv: i = 8(c-20)+cg*4+ct*2+(q>>1), f = xs[i]
            #pragma unroll
            for (int ct = 0; ct < 2; ct++) {
                const int i = 8 * (c - 20) + cg * 4 + ct * 2 + (q >> 1);
                #pragma unroll
                for (int et = 0; et < 2; et++) {
                    float f = bf2f(sF[i * 128 + (et ? e1 : e0)]);
                    #pragma unroll
                    for (int r = 0; r < 4; r++) {
                        float t0 = acc[ct][et][r] * f;
                        tpv[et][r][0] += t0 * svc[et][0];
                        tpv[et][r][1] += t0 * svc[et][1];
                        tpv[et][r][2] += t0 * svc[et][2];
                    }
                }
            }
        } else {                            // vv: i = cg*4+ct*2+(q>>1), f = xv[i]*ss
            #pragma unroll
            for (int ct = 0; ct < 2; ct++) {
                const int i = cg * 4 + ct * 2 + (q >> 1);
                #pragma unroll
                for (int et = 0; et < 2; et++) {
                    const int ee = et ? e1 : e0;
                    float x0 = bf2f(sF[(40 + 3 * i    ) * 128 + ee]) * ssc[et];
                    float x1 = bf2f(sF[(40 + 3 * i + 1) * 128 + ee]) * ssc[et];
                    float x2 = bf2f(sF[(40 + 3 * i + 2) * 128 + ee]) * ssc[et];
                    #pragma unroll
                    for (int r = 0; r < 4; r++) {
                        tpv[et][r][0] += acc[ct][et][r] * x0;
                        tpv[et][r][1] += acc[ct][et][r] * x1;
                        tpv[et][r][2] += acc[ct][et][r] * x2;
                    }
                }
            }
        }

        __syncthreads();   // chunk c reads + chunk c+1 writes complete
    }

    // ---- end-stage combine (padded overlays; final loop barrier drained everything) ----
    #pragma unroll
    for (int et = 0; et < 2; et++) {
        const int ee = et ? e1 : e0;
        #pragma unroll
        for (int ct = 0; ct < 2; ct++)
            #pragma unroll
            for (int r = 0; r < 4; r++)
                Ssc[(cg * 128 + ee) * 33 + ct * 16 + q * 4 + r] = tps[et][ct][r];
    }
    #pragma unroll
    for (int et = 0; et < 2; et++) {
        const int ee = et ? e1 : e0;
        #pragma unroll
        for (int r = 0; r < 4; r++)
            #pragma unroll
            for (int mm = 0; mm < 3; mm++) {
                float v = tpv[et][r][mm];
                v += __shfl_xor(v, 32, 64);
                if (q < 2)
                    Svec[(cg * 128 + ee) * 25 + (q * 4 + r) * 3 + mm] = v;
            }
    }
    __syncthreads();

    for (int idx = t; idx < 7168; idx += 512) {
        int e = idx / 56, d = idx - e * 56;
        float v;
        if (d < 32) {
            v = Ssc[e * 33 + d] + Ssc[(128 + e) * 33 + d];
        } else {
            int dd = d - 32;
            v = Svec[e * 25 + dd] + Svec[(128 + e) * 25 + dd];
        }
        tp[(size_t)(p0 + e) * DD + d] = v * PATH_NORMF;   // CSR position order
    }
}

// ---------------- K3: contiguous segment-mean + residual + per-block BN partials ----------------
__global__ __launch_bounds__(256) void gather_finalize(
    const float* __restrict__ tp, const int* __restrict__ row_start,
    const float* __restrict__ node_attr,
    float* __restrict__ ybuf, float* __restrict__ partial)
{
    __shared__ float ps[4][72];
    const int wv = threadIdx.x >> 6, lane = threadIdx.x & 63;
    const int n = blockIdx.x * 4 + wv;    // 4096 blocks
    const int beg = row_start[n], end = row_start[n + 1];
    if (lane < 56) {
        float acc = 0.f;
        for (int p = beg; p < end; p++)
            acc += tp[(size_t)p * DD + lane];   // fully coalesced, sequential
        float inv = 1.f / fmaxf((float)(end - beg), 1.f);
        float y = acc * inv + node_attr[(size_t)n * DD + lane];
        ybuf[(size_t)n * DD + lane] = y;
        if (lane < 32) {
            ps[wv][lane] = y;
            ps[wv][32 + lane] = y * y;
        } else {
            float vv = y * y;
            float v1 = __shfl_down(vv, 1, 64);
            float v2 = __shfl_down(vv, 2, 64);
            int l3 = lane - 32;
            if (l3 % 3 == 0) ps[wv][64 + l3 / 3] = vv + v1 + v2;
        }
    }
    __syncthreads();
    const int t = threadIdx.x;
    if (t < 72)
        partial[(size_t)blockIdx.x * 72 + t] = ps[0][t] + ps[1][t] + ps[2][t] + ps[3][t];
}

// ---------------- K4: reduce BN partials (no atomic contention) ----------------
__global__ __launch_bounds__(256) void bn_reduce(const float* __restrict__ partial,
                                                 float* __restrict__ stats)
{
    __shared__ float red[256];
    const int d = blockIdx.x;   // 0..71
    const int t = threadIdx.x;
    float a = 0.f;
    for (int i = t; i < 4096; i += 256) a += partial[(size_t)i * 72 + d];
    red[t] = a;
    __syncthreads();
    for (int off = 128; off > 0; off >>= 1) {
        if (t < off) red[t] += red[t + off];
        __syncthreads();
    }
    if (t == 0) stats[d] = red[0] * (1.f / 16384.f);
}

// ---------------- K5: batch-norm apply + write fp32 output ----------------
__global__ __launch_bounds__(256) void bn_apply(
    const float* __restrict__ ybuf, const float* __restrict__ stats,
    const float* __restrict__ gamma, const float* __restrict__ beta,
    float* __restrict__ out)
{
    const int i = blockIdx.x * 256 + threadIdx.x;   // 3584*256 = 917504
    const int n = i / 56;
    const int d = i - n * 56;
    float y = ybuf[i];
    float o;
    if (d < 32) {
        float mn  = stats[d];
        float var = stats[32 + d] - mn * mn;
        o = (y - mn) * rsqrtf(var + 1e-5f) * gamma[d] + beta[d];
    } else {
        int jv = (d - 32) / 3;
        o = y * rsqrtf(stats[64 + jv] + 1e-5f) * gamma[32 + jv];
    }
    out[i] = o;
}

// ---------------- launch ----------------
extern "C" void kernel_launch(void* const* d_in, const int* in_sizes, int n_in,
                              void* d_out, int out_size, void* d_ws, size_t ws_size,
                              hipStream_t stream)
{
    const float* node_attr = (const float*)d_in[0];
    const float* edge_attr = (const float*)d_in[1];
    const float* edge_sh   = (const float*)d_in[2];
    const float* W1        = (const float*)d_in[3];
    const float* b1        = (const float*)d_in[4];
    const float* W2        = (const float*)d_in[5];
    const float* b2        = (const float*)d_in[6];
    const float* gamma     = (const float*)d_in[7];
    const float* beta      = (const float*)d_in[8];
    const int*   eidx      = (const int*)d_in[9];

    char* ws = (char*)d_ws;
    u16*   W1f        = (u16*)(ws);                  // 32768 B
    u16*   W2f        = (u16*)(ws + 32768);          // 409600   -> 442368
    int*   deg        = (int*)(ws + 442368);         // 65536    -> 507904
    int*   row_start  = (int*)(ws + 507904);         // 65792    -> 573696
    int*   cursor     = (int*)(ws + 573696);         // 65536    -> 639232
    int*   edge_order = (int*)(ws + 639232);         // 524288   -> 1163520
    float* stats      = (float*)(ws + 1163520);      // 512      -> 1164032
    float* partial    = (float*)(ws + 1164032);      // 1179648  -> 2343680
    float* tp         = (float*)(ws + 2343680);      // 29360128 -> 31703808
    float* ybuf       = (float*)(ws + 31703808);     // 3670016  -> 35373824 (~35.4 MB)

    (void)hipMemsetAsync(deg, 0, 65536, stream);
    hipLaunchKernelGGL(prep,            dim3(1376), dim3(256),  0, stream,
                       W1, W2, W1f, W2f, eidx, deg);
    hipLaunchKernelGGL(deg_scan,        dim3(1),    dim3(1024), 0, stream, deg, row_start, cursor);
    hipLaunchKernelGGL(edge_scatter,    dim3(512),  dim3(256),  0, stream, eidx, cursor, edge_order);
    hipLaunchKernelGGL(tpconv,          dim3(1024), dim3(512),  0, stream,
                       node_attr, edge_attr, edge_sh, W1f, b1, W2f, b2, eidx, edge_order, tp);
    hipLaunchKernelGGL(gather_finalize, dim3(4096), dim3(256),  0, stream,
                       tp, row_start, node_attr, ybuf, partial);
    hipLaunchKernelGGL(bn_reduce,       dim3(72),   dim3(256),  0, stream, partial, stats);
    hipLaunchKernelGGL(bn_apply,        dim3(3584), dim3(256),  0, stream,
                       ybuf, stats, gamma, beta, (float*)d_out);
}